// Round 5
// baseline (176.909 us; speedup 1.0000x reference)
//
#include <hip/hip_runtime.h>

// Bilinear warp: out[b,c,i,j] = bilerp(trace[b,c], i + off0*256, j + off1*256)
// B=64, C=3, H=W=256. All fp32.
//
// v3b: same as v3 but nontemporal builtins use ext_vector_type(4) float
// (clang rejects HIP_vector_type float4 for __builtin_nontemporal_*).
// 4 pixels/thread in both kernels (16 independent float4 gathers in flight
// per thread -> latency hiding), nontemporal offset loads + output stores
// (keep per-XCD L2 for the NHWC gather planes), XCD-chunked swizzle.

typedef float f32x4 __attribute__((ext_vector_type(4)));

constexpr int Hc = 256;
constexpr int Wc = 256;
constexpr int Cc = 3;
constexpr int Bc = 64;
constexpr int HWc = Hc * Wc;  // 65536
constexpr size_t NHWC4_BYTES = (size_t)Bc * HWc * 4 * sizeof(float);  // 64 MiB

// ---------- Kernel 1: NCHW -> NHWC4 repack, 4 pixels/thread ----------
__global__ __launch_bounds__(256) void repack_nhwc4_x4(
    const float* __restrict__ trace, f32x4* __restrict__ nhwc)
{
    const int gtid = blockIdx.x * 256 + threadIdx.x;  // [0, B*HW/4)
    const int pb = gtid << 2;                         // pixel base
    const int b = pb >> 16;
    const int p = pb & (HWc - 1);

    const float* tb = trace + (size_t)b * Cc * HWc;
    const f32x4 c0 = *reinterpret_cast<const f32x4*>(tb + p);
    const f32x4 c1 = *reinterpret_cast<const f32x4*>(tb + HWc + p);
    const f32x4 c2 = *reinterpret_cast<const f32x4*>(tb + 2 * HWc + p);

    f32x4* dst = nhwc + (size_t)b * HWc + p;
    dst[0] = (f32x4){c0.x, c1.x, c2.x, 0.0f};
    dst[1] = (f32x4){c0.y, c1.y, c2.y, 0.0f};
    dst[2] = (f32x4){c0.z, c1.z, c2.z, 0.0f};
    dst[3] = (f32x4){c0.w, c1.w, c2.w, 0.0f};
}

// ---------- Kernel 2: gather + bilerp, 4 pixels/thread ----------
__global__ __launch_bounds__(256) void warp_gather_nhwc4_x4(
    const f32x4* __restrict__ nhwc,
    const float* __restrict__ offsets,
    float* __restrict__ out)
{
    // 4096 blocks; XCD-chunked swizzle: XCD k owns blocks [k*512,(k+1)*512).
    const int bid = blockIdx.x;
    const int sb = ((bid & 7) << 9) | (bid >> 3);
    const int gtid = sb * 256 + threadIdx.x;
    const int pb = gtid << 2;          // base pixel index in [0, B*HW)
    const int b = pb >> 16;
    const int p = pb & (HWc - 1);      // 4-aligned, so p..p+3 same row
    const int i = p >> 8;
    const int j = p & (Wc - 1);

    const float* offb = offsets + (size_t)b * 2 * HWc;
    const f32x4 ox4 = __builtin_nontemporal_load(
        reinterpret_cast<const f32x4*>(offb + p));
    const f32x4 oy4 = __builtin_nontemporal_load(
        reinterpret_cast<const f32x4*>(offb + HWc + p));

    const float oxa[4] = {ox4.x, ox4.y, ox4.z, ox4.w};
    const float oya[4] = {oy4.x, oy4.y, oy4.z, oy4.w};

    float fx[4], fy[4];
    int a00[4], a01[4], a10[4], a11[4];
    #pragma unroll
    for (int k = 0; k < 4; ++k) {
        const float sx = fminf(fmaxf((float)i + oxa[k] * 256.0f, 0.0f), 255.0f);
        const float sy = fminf(fmaxf((float)(j + k) + oya[k] * 256.0f, 0.0f), 255.0f);
        const float flx = floorf(sx);
        const float fly = floorf(sy);
        const int x0 = (int)flx;
        const int y0 = (int)fly;
        const int x1 = (int)ceilf(sx);
        const int y1 = (int)ceilf(sy);
        fx[k] = sx - flx;
        fy[k] = sy - fly;
        a00[k] = (x0 << 8) + y0;
        a01[k] = (x0 << 8) + y1;
        a10[k] = (x1 << 8) + y0;
        a11[k] = (x1 << 8) + y1;
    }

    const f32x4* tb = nhwc + (size_t)b * HWc;
    f32x4 v00[4], v01[4], v10[4], v11[4];
    #pragma unroll
    for (int k = 0; k < 4; ++k) v00[k] = tb[a00[k]];
    #pragma unroll
    for (int k = 0; k < 4; ++k) v01[k] = tb[a01[k]];
    #pragma unroll
    for (int k = 0; k < 4; ++k) v10[k] = tb[a10[k]];
    #pragma unroll
    for (int k = 0; k < 4; ++k) v11[k] = tb[a11[k]];

    // Per-channel results for 4 consecutive pixels -> 3 nontemporal dwordx4 stores
    float r0[4], r1[4], r2[4];
    #pragma unroll
    for (int k = 0; k < 4; ++k) {
        {
            const float xu = v00[k].x + (v10[k].x - v00[k].x) * fx[k];
            const float xb = v01[k].x + (v11[k].x - v01[k].x) * fx[k];
            r0[k] = xu + (xb - xu) * fy[k];
        }
        {
            const float xu = v00[k].y + (v10[k].y - v00[k].y) * fx[k];
            const float xb = v01[k].y + (v11[k].y - v01[k].y) * fx[k];
            r1[k] = xu + (xb - xu) * fy[k];
        }
        {
            const float xu = v00[k].z + (v10[k].z - v00[k].z) * fx[k];
            const float xb = v01[k].z + (v11[k].z - v01[k].z) * fx[k];
            r2[k] = xu + (xb - xu) * fy[k];
        }
    }

    float* ob = out + (size_t)b * Cc * HWc;
    __builtin_nontemporal_store((f32x4){r0[0], r0[1], r0[2], r0[3]},
                                reinterpret_cast<f32x4*>(ob + p));
    __builtin_nontemporal_store((f32x4){r1[0], r1[1], r1[2], r1[3]},
                                reinterpret_cast<f32x4*>(ob + HWc + p));
    __builtin_nontemporal_store((f32x4){r2[0], r2[1], r2[2], r2[3]},
                                reinterpret_cast<f32x4*>(ob + 2 * HWc + p));
}

// ---------- Fallback (if workspace too small): fused kernel ----------
__global__ __launch_bounds__(256) void warp_bilinear_kernel(
    const float* __restrict__ trace,
    const float* __restrict__ offsets,
    float* __restrict__ out)
{
    const int idx = blockIdx.x * blockDim.x + threadIdx.x;
    const int b = idx >> 16;
    const int p = idx & (HWc - 1);
    const int i = p >> 8;
    const int j = p & (Wc - 1);

    const float* offb = offsets + (size_t)b * 2 * HWc;
    const float ox = offb[p] * 256.0f;
    const float oy = offb[HWc + p] * 256.0f;

    const float sx = fminf(fmaxf((float)i + ox, 0.0f), 255.0f);
    const float sy = fminf(fmaxf((float)j + oy, 0.0f), 255.0f);

    const float flx = floorf(sx);
    const float fly = floorf(sy);
    const int x0 = (int)flx;
    const int y0 = (int)fly;
    const int x1 = (int)ceilf(sx);
    const int y1 = (int)ceilf(sy);
    const float fx = sx - flx;
    const float fy = sy - fly;

    const int r0 = x0 << 8;
    const int r1 = x1 << 8;

    const float* tb = trace + (size_t)b * Cc * HWc;
    float* ob = out + (size_t)b * Cc * HWc;

    #pragma unroll
    for (int c = 0; c < Cc; ++c) {
        const float* tc = tb + c * HWc;
        const float v00 = tc[r0 + y0];
        const float v01 = tc[r0 + y1];
        const float v10 = tc[r1 + y0];
        const float v11 = tc[r1 + y1];
        const float xu = v00 + (v10 - v00) * fx;
        const float xb = v01 + (v11 - v01) * fx;
        ob[c * HWc + p] = xu + (xb - xu) * fy;
    }
}

extern "C" void kernel_launch(void* const* d_in, const int* in_sizes, int n_in,
                              void* d_out, int out_size, void* d_ws, size_t ws_size,
                              hipStream_t stream) {
    const float* trace = (const float*)d_in[0];
    const float* offsets = (const float*)d_in[1];
    float* out = (float*)d_out;

    const int total = Bc * HWc;  // 4,194,304 pixels

    if (ws_size >= NHWC4_BYTES) {
        f32x4* nhwc = (f32x4*)d_ws;
        const int threads = total / 4;          // 1,048,576
        const int grid = threads / 256;         // 4096 blocks
        repack_nhwc4_x4<<<grid, 256, 0, stream>>>(trace, nhwc);
        warp_gather_nhwc4_x4<<<grid, 256, 0, stream>>>(nhwc, offsets, out);
    } else {
        warp_bilinear_kernel<<<total / 256, 256, 0, stream>>>(trace, offsets, out);
    }
}

// Round 7
// 156.647 us; speedup vs baseline: 1.1293x; 1.1293x over previous
//
#include <hip/hip_runtime.h>

// Bilinear warp: out[b,c,i,j] = bilerp(trace[b,c], i + off0*256, j + off1*256)
// B=64, C=3, H=W=256. All fp32 in/out.
//
// v4 (resubmit after GPU timeout): row-pair fp16 packing. Workspace entry
// (16 B) at (b,x,y):
//   {fp16 c0,c1,c2,pad of pixel(x,y),  fp16 c0,c1,c2,pad of pixel(min(x+1,255),y)}
// One dwordx4 gather at (x0,y0) delivers BOTH v00 and v10 (x1==x0+1 whenever
// fx>0; when fx==0 the partner is multiplied by 0). So bilinear needs only
// 2 gathers/pixel (was 4) -> halves the L1/L2 transaction count that bounds
// the gather kernel. Weights/arithmetic stay fp32, reference math order.

typedef _Float16 f16;
typedef f16 f16x8 __attribute__((ext_vector_type(8)));  // 16 B entry

constexpr int Hc = 256;
constexpr int Wc = 256;
constexpr int Cc = 3;
constexpr int Bc = 64;
constexpr int HWc = Hc * Wc;  // 65536
constexpr size_t PAIRED_BYTES = (size_t)Bc * HWc * sizeof(f16x8);  // 64 MiB

// ---------- Kernel 1: NCHW fp32 -> paired fp16 repack ----------
// Block = 256 threads (thread = column y), each block does 4 consecutive rows
// of one batch image. Reads rows x..x+4 (row 256 clamped), writes 4 entries.
__global__ __launch_bounds__(256) void repack_pair_f16(
    const float* __restrict__ trace, f16x8* __restrict__ paired)
{
    const int blk = blockIdx.x;          // [0, 64*64)
    const int b = blk >> 6;              // batch
    const int xg = (blk & 63) << 2;      // row group base (0,4,...,252)
    const int y = threadIdx.x;           // column

    const float* tb = trace + (size_t)b * Cc * HWc;

    float rv[5][3];
    #pragma unroll
    for (int r = 0; r < 5; ++r) {
        const int xr = (xg + r < Hc) ? (xg + r) : (Hc - 1);
        const int base = (xr << 8) + y;
        #pragma unroll
        for (int c = 0; c < Cc; ++c) rv[r][c] = tb[c * HWc + base];
    }

    f16x8* dst = paired + (size_t)b * HWc + (xg << 8) + y;
    #pragma unroll
    for (int r = 0; r < 4; ++r) {
        f16x8 e;
        e[0] = (f16)rv[r][0];
        e[1] = (f16)rv[r][1];
        e[2] = (f16)rv[r][2];
        e[3] = (f16)0.0f;
        e[4] = (f16)rv[r + 1][0];
        e[5] = (f16)rv[r + 1][1];
        e[6] = (f16)rv[r + 1][2];
        e[7] = (f16)0.0f;
        dst[r << 8] = e;
    }
}

// ---------- Kernel 2: gather + bilerp, 1 pixel/thread, 2 gathers ----------
__global__ __launch_bounds__(256) void warp_gather_pair_f16(
    const f16x8* __restrict__ paired,
    const float* __restrict__ offsets,
    float* __restrict__ out)
{
    // 16384 blocks; XCD-chunked swizzle: XCD k owns blocks [k*2048,(k+1)*2048).
    const int bid = blockIdx.x;
    const int sb = ((bid & 7) << 11) | (bid >> 3);
    const int idx = (sb << 8) | threadIdx.x;

    const int b = idx >> 16;
    const int p = idx & (HWc - 1);
    const int i = p >> 8;
    const int j = p & (Wc - 1);

    const float* offb = offsets + (size_t)b * 2 * HWc;
    const float ox = offb[p] * 256.0f;
    const float oy = offb[HWc + p] * 256.0f;

    const float sx = fminf(fmaxf((float)i + ox, 0.0f), 255.0f);
    const float sy = fminf(fmaxf((float)j + oy, 0.0f), 255.0f);

    const float flx = floorf(sx);
    const float fly = floorf(sy);
    const int x0 = (int)flx;
    const int y0 = (int)fly;
    const int y1 = (int)ceilf(sy);
    const float fx = sx - flx;
    const float fy = sy - fly;

    const f16x8* tb = paired + (size_t)b * HWc + (x0 << 8);
    const f16x8 e0 = tb[y0];   // v00 (lo) + v10 (hi)
    const f16x8 e1 = tb[y1];   // v01 (lo) + v11 (hi)

    float* ob = out + (size_t)b * Cc * HWc;
    #pragma unroll
    for (int c = 0; c < Cc; ++c) {
        const float v00 = (float)e0[c];
        const float v10 = (float)e0[c + 4];
        const float v01 = (float)e1[c];
        const float v11 = (float)e1[c + 4];
        const float xu = v00 + (v10 - v00) * fx;
        const float xb = v01 + (v11 - v01) * fx;
        ob[c * HWc + p] = xu + (xb - xu) * fy;
    }
}

// ---------- Fallback (if workspace too small): fused fp32 kernel ----------
__global__ __launch_bounds__(256) void warp_bilinear_kernel(
    const float* __restrict__ trace,
    const float* __restrict__ offsets,
    float* __restrict__ out)
{
    const int idx = blockIdx.x * blockDim.x + threadIdx.x;
    const int b = idx >> 16;
    const int p = idx & (HWc - 1);
    const int i = p >> 8;
    const int j = p & (Wc - 1);

    const float* offb = offsets + (size_t)b * 2 * HWc;
    const float ox = offb[p] * 256.0f;
    const float oy = offb[HWc + p] * 256.0f;

    const float sx = fminf(fmaxf((float)i + ox, 0.0f), 255.0f);
    const float sy = fminf(fmaxf((float)j + oy, 0.0f), 255.0f);

    const float flx = floorf(sx);
    const float fly = floorf(sy);
    const int x0 = (int)flx;
    const int y0 = (int)fly;
    const int x1 = (int)ceilf(sx);
    const int y1 = (int)ceilf(sy);
    const float fx = sx - flx;
    const float fy = sy - fly;

    const int r0 = x0 << 8;
    const int r1 = x1 << 8;

    const float* tb = trace + (size_t)b * Cc * HWc;
    float* ob = out + (size_t)b * Cc * HWc;

    #pragma unroll
    for (int c = 0; c < Cc; ++c) {
        const float* tc = tb + c * HWc;
        const float v00 = tc[r0 + y0];
        const float v01 = tc[r0 + y1];
        const float v10 = tc[r1 + y0];
        const float v11 = tc[r1 + y1];
        const float xu = v00 + (v10 - v00) * fx;
        const float xb = v01 + (v11 - v01) * fx;
        ob[c * HWc + p] = xu + (xb - xu) * fy;
    }
}

extern "C" void kernel_launch(void* const* d_in, const int* in_sizes, int n_in,
                              void* d_out, int out_size, void* d_ws, size_t ws_size,
                              hipStream_t stream) {
    const float* trace = (const float*)d_in[0];
    const float* offsets = (const float*)d_in[1];
    float* out = (float*)d_out;

    const int total = Bc * HWc;  // 4,194,304 pixels

    if (ws_size >= PAIRED_BYTES) {
        f16x8* paired = (f16x8*)d_ws;
        repack_pair_f16<<<Bc * (Hc / 4), 256, 0, stream>>>(trace, paired);   // 4096 blocks
        warp_gather_pair_f16<<<total / 256, 256, 0, stream>>>(paired, offsets, out);  // 16384
    } else {
        warp_bilinear_kernel<<<total / 256, 256, 0, stream>>>(trace, offsets, out);
    }
}